// Round 11
// baseline (241.950 us; speedup 1.0000x reference)
//
#include <hip/hip_runtime.h>
#include <hip/hip_bf16.h>

#define SEQ   2048
#define NH    12
#define MTOK  8192   // 4*2048 token rows

typedef __attribute__((ext_vector_type(8))) short short8;
typedef __attribute__((ext_vector_type(4))) short short4v;
typedef __attribute__((ext_vector_type(4))) float f32x4;
typedef __attribute__((ext_vector_type(16))) float f32x16;
typedef __attribute__((ext_vector_type(2))) unsigned uint2v;

__device__ inline short f2bf(float x) {
  __hip_bfloat16 h = __float2bfloat16(x);
  return *(short*)&h;
}

#define GLL(gp, lp) __builtin_amdgcn_global_load_lds( \
    (const __attribute__((address_space(1))) void*)(gp), \
    (__attribute__((address_space(3))) void*)(lp), 16, 0, 0)

// width-4 GLL for the 64-float mask slice (lane i -> dst + i*4)
#define GLL4(gp, lp) __builtin_amdgcn_global_load_lds( \
    (const __attribute__((address_space(1))) void*)(gp), \
    (__attribute__((address_space(3))) void*)(lp), 4, 0, 0)

#define MFMA(a, b, c) __builtin_amdgcn_mfma_f32_16x16x32_bf16(a, b, c, 0, 0, 0)

// 32x32x16 bf16 MFMA — full K-rate (16x16x16 runs at half FLOP/slot)
#if !defined(__HIP_DEVICE_COMPILE__)
#define MFMA32(a, b, c) (c)
#else
#define MFMA32(a, b, c) __builtin_amdgcn_mfma_f32_32x32x16_bf16(a, b, c, 0, 0, 0)
#endif

// native exp2 (1 VALU op) hedge
#if !defined(__HIP_DEVICE_COMPILE__)
#define EXP2(x) (x)
#elif __has_builtin(__builtin_amdgcn_exp2f)
#define EXP2(x) __builtin_amdgcn_exp2f(x)
#else
#define EXP2(x) __expf((x) * 0.6931471805599453f)
#endif

// pack two fp32 -> bf16x2 dword (round-half-away; inputs finite). 3 VALU ops.
__device__ inline unsigned pack2bf(float a, float b) {
  unsigned ua = __float_as_uint(a) + 0x8000u;
  unsigned ub = __float_as_uint(b) + 0x8000u;
#if defined(__HIP_DEVICE_COMPILE__) && __has_builtin(__builtin_amdgcn_perm)
  return __builtin_amdgcn_perm(ub, ua, 0x07060302u);
#else
  return (ub & 0xFFFF0000u) | (ua >> 16);
#endif
}

// truncate-pack two fp32 -> bf16x2 (ONE VALU op: v_perm_b32). a->low, b->high.
// Truncation bias cancels in O/l since l sums the SAME truncated fragments.
__device__ inline unsigned packtrunc2(float a, float b) {
#if defined(__HIP_DEVICE_COMPILE__) && __has_builtin(__builtin_amdgcn_perm)
  return __builtin_amdgcn_perm(__float_as_uint(b), __float_as_uint(a),
                               0x07060302u);
#else
  return (__float_as_uint(b) & 0xFFFF0000u) | (__float_as_uint(a) >> 16);
#endif
}

// v_permlane32_swap_b32: ISA semantics — swaps rows 32..63 of vdst(a) with
// rows 0..31 of vsrc(b):  a'[32+i]=b[i], b'[i]=a[32+i]; others keep.
// Returns {a', b'}. Fallback: shfl(lane^32)+select, identical semantics.
__device__ inline uint2v lane32swap(unsigned a, unsigned b) {
#if defined(__HIP_DEVICE_COMPILE__) && __has_builtin(__builtin_amdgcn_permlane32_swap)
  return __builtin_amdgcn_permlane32_swap(a, b, false, false);
#else
  int lane = (int)(threadIdx.x & 63);
  unsigned xa = (unsigned)__shfl((int)a, lane ^ 32, 64);
  unsigned xb = (unsigned)__shfl((int)b, lane ^ 32, 64);
  bool hi = lane >= 32;
  uint2v r;
  r.x = hi ? xb : a;   // a': lo keeps a, hi gets lo-partner's b
  r.y = hi ? b : xa;   // b': lo gets hi-partner's a, hi keeps b
  return r;
#endif
}

union PackFrag {
  unsigned u[2];
  short4v s;
};

union Frag8 {
  unsigned u[4];
  short8 s;
};

// log2(e)*0.125 folded into Q so p = exp2(S + maskbias)
#define QSCALE 0.18033688011112042f
#define MBSCALE -14426.950408889634f  // -10000*log2(e)

// ---------------------------------------------------------------------------
// Fused prep: hs->Xb bf16 | Wq|Wk|Wv->Wqkvb, Wo->Wob | mask->mbias
// ---------------------------------------------------------------------------
__global__ __launch_bounds__(256) void prep(
    const float* __restrict__ hs, const float* __restrict__ Wq,
    const float* __restrict__ Wk, const float* __restrict__ Wv,
    const float* __restrict__ Wo, const float* __restrict__ mask,
    short* __restrict__ Xb, short* __restrict__ Wqkvb,
    short* __restrict__ Wob, float* __restrict__ mbias) {
  int bid = blockIdx.x;
  if (bid < 6144) {
    int i = bid * 256 + threadIdx.x;     // 8192*192 float4s
    float4 v = ((const float4*)hs)[i];
    short4v o;
    o[0] = f2bf(v.x); o[1] = f2bf(v.y); o[2] = f2bf(v.z); o[3] = f2bf(v.w);
    ((short4v*)Xb)[i] = o;
  } else if (bid < 6144 + 2304) {
    int idx = (bid - 6144) * 256 + threadIdx.x;  // 3072*192
    int r = idx / 192, c = (idx - r * 192) * 4;
    const float* src;
    short* dst;
    int rr;
    if (r < 768)       { src = Wq; rr = r;        dst = Wqkvb; }
    else if (r < 1536) { src = Wk; rr = r - 768;  dst = Wqkvb; }
    else if (r < 2304) { src = Wv; rr = r - 1536; dst = Wqkvb; }
    else               { src = Wo; rr = r - 2304; dst = Wob; r = rr; }
    float4 v = *(const float4*)&src[(size_t)rr * 768 + c];
    short4v o;
    o[0] = f2bf(v.x); o[1] = f2bf(v.y); o[2] = f2bf(v.z); o[3] = f2bf(v.w);
    *(short4v*)&dst[(size_t)r * 768 + c] = o;
  } else {
    int i = (bid - 6144 - 2304) * 256 + threadIdx.x;
    if (i < MTOK) mbias[i] = (1.f - mask[i]) * MBSCALE;
  }
}

// ---------------------------------------------------------------------------
// GEMM 8-phase core (T3+T4+T5, guide §5.5): 256x128 tile, BK=64, 512 thr
// (8 waves 2M x 4N, per-wave 128x32 out), LDS 96KB double-buffered. Data-path
// (fragments, XOR-chunk swizzle, GLL staging pattern) is bit-identical to the
// verified BK64 core — only geometry + schedule changed. Per K-tile: 4 phases
// {ds_read mt-pair (+B & 6 GLLs for t+1 in p0) -> bar -> setprio1 8xMFMA
// setprio0 -> bar}; iteration start waits vmcnt(0) == exact count (only
// next-tile's 6 outstanding, issued ~3.5 phases earlier => latency covered).
// Buf-overwrite safe: t+1's GLLs target the buffer whose reads finished
// before the previous iteration's last phase barrier.
// ---------------------------------------------------------------------------
#define GS8(kk, s) do {                                                       \
    const int k0g = ((kk) % 12) * 64;                                         \
    _Pragma("unroll") for (int g = 0; g < 4; ++g)                             \
      GLL(gA[g] + k0g, &As[s][(wid * 32 + g * 8) * 64]);                      \
    _Pragma("unroll") for (int g = 0; g < 2; ++g)                             \
      GLL(gB[g] + k0g, &Bs[s][(wid * 16 + g * 8) * 64]);                      \
  } while (0)

#define GEMM_8P_CORE(Aptr, Bptr)                                              \
  __shared__ __align__(16) short As[2][256 * 64];                             \
  __shared__ __align__(16) short Bs[2][128 * 64];                             \
  const int t = threadIdx.x;                                                  \
  const int wid = t >> 6, lane = t & 63, l15 = lane & 15, quad = lane >> 4;   \
  const int bm = blockIdx.x * 256, bn = blockIdx.y * 128;                     \
  const int wm = wid & 1, wn = wid >> 1;                                      \
  const int srow8 = lane >> 3, schunk = lane & 7;                             \
  const int scol = (schunk ^ srow8) * 8;                                      \
  f32x4 acc[8][2] = {};                                                       \
  const short *gA[4], *gB[2];                                                 \
  _Pragma("unroll") for (int g = 0; g < 4; ++g)                               \
    gA[g] = (Aptr) + (size_t)(bm + wid * 32 + g * 8 + srow8) * 768 + scol;    \
  _Pragma("unroll") for (int g = 0; g < 2; ++g)                               \
    gB[g] = (Bptr) + (size_t)(bn + wid * 16 + g * 8 + srow8) * 768 + scol;    \
  GS8(0, 0);                                                                  \
  asm volatile("s_waitcnt vmcnt(0)" ::: "memory");                            \
  __builtin_amdgcn_s_barrier();                                               \
  __builtin_amdgcn_sched_barrier(0);                                          \
  for (int ti = 0; ti < 12; ++ti) {                                           \
    const int cur = ti & 1;                                                   \
    if (ti) {                                                                 \
      asm volatile("s_waitcnt vmcnt(0)" ::: "memory");                        \
      __builtin_amdgcn_s_barrier();                                           \
      __builtin_amdgcn_sched_barrier(0);                                      \
    }                                                                         \
    short8 bfr[2][2];                                                         \
    _Pragma("unroll") for (int p = 0; p < 4; ++p) {                           \
      short8 afr[2][2];                                                       \
      _Pragma("unroll") for (int j = 0; j < 2; ++j)                           \
        _Pragma("unroll") for (int ks = 0; ks < 2; ++ks)                      \
          afr[j][ks] = *(const short8*)&As[cur][                              \
              (wm * 128 + (p * 2 + j) * 16 + l15) * 64 +                      \
              (((ks * 4 + quad) ^ (l15 & 7)) * 8)];                           \
      if (p == 0) {                                                           \
        _Pragma("unroll") for (int nt = 0; nt < 2; ++nt)                      \
          _Pragma("unroll") for (int ks = 0; ks < 2; ++ks)                    \
            bfr[nt][ks] = *(const short8*)&Bs[cur][                           \
                (wn * 32 + nt * 16 + l15) * 64 +                              \
                (((ks * 4 + quad) ^ (l15 & 7)) * 8)];                         \
        GS8(ti + 1, cur ^ 1);                                                 \
      }                                                                       \
      __builtin_amdgcn_s_barrier();                                           \
      __builtin_amdgcn_sched_barrier(0);                                      \
      __builtin_amdgcn_s_setprio(1);                                          \
      _Pragma("unroll") for (int ks = 0; ks < 2; ++ks)                        \
        _Pragma("unroll") for (int j = 0; j < 2; ++j)                         \
          _Pragma("unroll") for (int nt = 0; nt < 2; ++nt)                    \
            acc[p * 2 + j][nt] =                                              \
                MFMA(afr[j][ks], bfr[nt][ks], acc[p * 2 + j][nt]);            \
      __builtin_amdgcn_s_setprio(0);                                          \
      __builtin_amdgcn_s_barrier();                                           \
      __builtin_amdgcn_sched_barrier(0);                                      \
    }                                                                         \
  }

// ---------------------------------------------------------------------------
__global__ __launch_bounds__(512, 2) void gemm_qkv(
    const short* __restrict__ A, const short* __restrict__ B,
    const float* __restrict__ bq, const float* __restrict__ bk,
    const float* __restrict__ bv, short* __restrict__ Qb,
    short* __restrict__ Kb, short* __restrict__ Vt) {
  GEMM_8P_CORE(A, B)

  const int seg = bn >= 1536 ? 2 : (bn >= 768 ? 1 : 0);
  const float* bias = seg == 0 ? bq : (seg == 1 ? bk : bv);
  const int colbase = bn - seg * 768;

  if (seg < 2) {
    short* dst = seg == 0 ? Qb : Kb;
    const float sc = seg == 0 ? QSCALE : 1.f;
#pragma unroll
    for (int mt = 0; mt < 8; ++mt)
#pragma unroll
      for (int nt = 0; nt < 2; ++nt) {
        int col = colbase + wn * 32 + nt * 16 + l15;
        float bias_v = bias[col];
#pragma unroll
        for (int i = 0; i < 4; ++i) {
          int row = bm + wm * 128 + mt * 16 + quad * 4 + i;
          dst[(size_t)row * 768 + col] = f2bf((acc[mt][nt][i] + bias_v) * sc);
        }
      }
  } else {
#pragma unroll
    for (int mt = 0; mt < 8; ++mt) {
      int row0 = bm + wm * 128 + mt * 16 + quad * 4;
      int b_ = row0 >> 11, s = row0 & 2047;
#pragma unroll
      for (int nt = 0; nt < 2; ++nt) {
        int col = colbase + wn * 32 + nt * 16 + l15;
        float bias_v = bias[col];
        int h = col >> 6, d = col & 63;
        short4v pv;
#pragma unroll
        for (int i = 0; i < 4; ++i) pv[i] = f2bf(acc[mt][nt][i] + bias_v);
        *(short4v*)&Vt[(((size_t)b_ * NH + h) * 64 + d) * 2048 + s] = pv;
      }
    }
  }
}

// ---------------------------------------------------------------------------
__global__ __launch_bounds__(512, 2) void gemm_out(
    const short* __restrict__ A, const short* __restrict__ B,
    const float* __restrict__ bias, float* __restrict__ C) {
  GEMM_8P_CORE(A, B)

#pragma unroll
  for (int mt = 0; mt < 8; ++mt)
#pragma unroll
    for (int nt = 0; nt < 2; ++nt) {
      int col = bn + wn * 32 + nt * 16 + l15;
      float bias_v = bias[col];
#pragma unroll
      for (int i = 0; i < 4; ++i) {
        int row = bm + wm * 128 + mt * 16 + quad * 4 + i;
        C[(size_t)row * 768 + col] = acc[mt][nt][i] + bias_v;
      }
    }
}

// ---------------------------------------------------------------------------
// attn_v13 (R6, verified 68.8us): v12 32x32-MFMA math + ring-3 LDS, counted
// vmcnt(5), mask in LDS. Unchanged (R8's setprio graft regressed; reverted).
// ---------------------------------------------------------------------------
__global__ __launch_bounds__(256, 3) void attn_v13(
    const short* __restrict__ Qb, const short* __restrict__ Kb,
    const short* __restrict__ Vt, const float* __restrict__ maskb,
    short* __restrict__ Ctx) {
  __shared__ __align__(16) short Ks[3][64 * 64];   // [slot][key][dchunk^swz]
  __shared__ __align__(16) short Vs[3][64 * 64];   // [slot][d][keychunk^swz]
  __shared__ __align__(16) float Mbs[3][64];       // [slot][key] mask bias
  const int t = threadIdx.x;
  const int w = t >> 6, lane = t & 63, l31 = lane & 31, hi = lane >> 5;
  const int bh = blockIdx.x, b = bh / NH, h = bh % NH;
  const int q0 = blockIdx.y * 128;

  // Q B-fragments: qb[kc] = Q[q=l31][d = kc*16 + hi*8 + 0..7]
  short8 qb[4];
  {
    int rowq = b * 2048 + q0 + w * 32 + l31;
    const short* qp = &Qb[(size_t)rowq * 768 + h * 64 + hi * 8];
#pragma unroll
    for (int kc = 0; kc < 4; ++kc) qb[kc] = *(const short8*)&qp[kc * 16];
  }

  f32x16 O0 = {}, O1 = {}, lacc = {};
  short8 ones8;
#pragma unroll
  for (int j = 0; j < 8; ++j) ones8[j] = (short)0x3F80;  // bf16 1.0

  // staging: each wave stages 16 K-rows + 16 V-rows + the 64-float mb slice
  const int r0 = w * 16 + (lane >> 3);
  const int pc = lane & 7;
  const int swz0 = (pc ^ (r0 & 7)) * 8;
  const int swz1 = (pc ^ ((r0 + 8) & 7)) * 8;
  const short* gK0 = Kb + (size_t)(b * 2048 + r0) * 768 + h * 64 + swz0;
  const short* gK1 = Kb + (size_t)(b * 2048 + r0 + 8) * 768 + h * 64 + swz1;
  const short* gV0 = Vt + ((size_t)bh * 64 + r0) * 2048 + swz0;
  const short* gV1 = Vt + ((size_t)bh * 64 + r0 + 8) * 2048 + swz1;
  const float* gmb = maskb + b * 2048 + lane;  // per-lane f32 for GLL4
  const int rs = l31 & 7;  // read-side swizzle key (row&7 for both 32-blocks)

  // issue the 5 GLLs for tile tt into ring slot s (mb first -> group of 5)
#define STAGE(tt, s) do {                                                     \
    const size_t kn = (size_t)(((tt) & 31) * 64);                             \
    GLL4(gmb + kn, &Mbs[s][0]);                                               \
    GLL(gK0 + kn * 768, &Ks[s][(w * 16) * 64]);                               \
    GLL(gK1 + kn * 768, &Ks[s][(w * 16 + 8) * 64]);                           \
    GLL(gV0 + kn, &Vs[s][(w * 16) * 64]);                                     \
    GLL(gV1 + kn, &Vs[s][(w * 16 + 8) * 64]);                                 \
  } while (0)

#define TILE_SYNC() do {                                                      \
    asm volatile("s_waitcnt vmcnt(5)" ::: "memory");                          \
    __builtin_amdgcn_s_barrier();                                             \
    __builtin_amdgcn_sched_barrier(0);                                        \
  } while (0)

  // prologue: tiles 0,1 in flight; wait for tile 0 only (vmcnt(5) leaves
  // tile 1's five GLLs outstanding; also drains the older Q loads).
  STAGE(0, 0);
  STAGE(1, 1);
  TILE_SYNC();

  int cur = 0;
  for (int ti = 0; ti < 32; ++ti) {
    const int nx2 = (cur == 0) ? 2 : cur - 1;  // (ti+2)%3
    STAGE(ti + 2, nx2);                        // depth-2 prefetch (wraps; unread)

    short8 pfrag[4];  // PV B-fragments, one per 16-key chunk

#pragma unroll
    for (int kb2 = 0; kb2 < 2; ++kb2) {
      // S^T[key][q], keys kb2*32..+31: seed with maskbias from LDS
      // (acc reg 4g+i holds key kb2*32 + 8g + 4hi + i)
      f32x16 S;
#pragma unroll
      for (int g = 0; g < 4; ++g) {
        f32x4 m4 = *(const f32x4*)&Mbs[cur][kb2 * 32 + g * 8 + hi * 4];
        S[4 * g + 0] = m4[0]; S[4 * g + 1] = m4[1];
        S[4 * g + 2] = m4[2]; S[4 * g + 3] = m4[3];
      }
      // K A-frags: K[key = kb2*32 + l31][d = kc*16 + hi*8 + 0..7]
#pragma unroll
      for (int kc = 0; kc < 4; ++kc) {
        short8 ka = *(const short8*)&Ks[cur][(kb2 * 32 + l31) * 64 +
                                            (((kc * 2 + hi) ^ rs) * 8)];
        S = MFMA32(ka, qb[kc], S);
      }
      // p = exp2(S) -> truncate-pack -> dwords pk[g][m] = keys 8g+4hi+{2m,2m+1}
      unsigned pk[4][2];
#pragma unroll
      for (int g = 0; g < 4; ++g) {
        float p0 = EXP2(S[4 * g + 0]);
        float p1 = EXP2(S[4 * g + 1]);
        float p2 = EXP2(S[4 * g + 2]);
        float p3 = EXP2(S[4 * g + 3]);
        pk[g][0] = packtrunc2(p0, p1);
        pk[g][1] = packtrunc2(p2, p3);
      }
      // permlane32_swap -> B-frags (keys hi*8+{0..7} per 16-key chunk)
#pragma unroll
      for (int half = 0; half < 2; ++half) {
        Frag8 f;
        uint2v ra = lane32swap(pk[half * 2][0], pk[half * 2 + 1][0]);
        uint2v rb = lane32swap(pk[half * 2][1], pk[half * 2 + 1][1]);
        f.u[0] = ra.x;  // keys +{0,1}
        f.u[1] = rb.x;  // keys +{2,3}
        f.u[2] = ra.y;  // keys +{4,5}
        f.u[3] = rb.y;  // keys +{6,7}
        pfrag[kb2 * 2 + half] = f.s;
      }
    }

    // l += 1 . P^T  (every D row = running l[q]; consumes truncated pfrag)
#pragma unroll
    for (int c = 0; c < 4; ++c) lacc = MFMA32(ones8, pfrag[c], lacc);

    // O^T += V^T . P^T : A = V^T[d = db*32 + l31][key = c*16 + hi*8 + 0..7]
#pragma unroll
    for (int c = 0; c < 4; ++c) {
      short8 av0 = *(const short8*)&Vs[cur][(l31) * 64 +
                                           (((c * 2 + hi) ^ rs) * 8)];
      short8 av1 = *(const short8*)&Vs[cur][(32 + l31) * 64 +
                                           (((c * 2 + hi) ^ rs) * 8)];
      O0 = MFMA32(av0, pfrag[c], O0);
      O1 = MFMA32(av1, pfrag[c], O1);
    }

    TILE_SYNC();  // tile ti+1 ready; tile ti+2's 5 GLLs stay in flight
    cur = (cur == 2) ? 0 : cur + 1;
  }

  // epilogue: O reg 4g+i = O^T[d = db*32 + 8g + 4hi + i][q = l31]
  {
    float inv = 1.f / lacc[0];
    int rowq = b * 2048 + q0 + w * 32 + l31;
    short* cp = &Ctx[(size_t)rowq * 768 + h * 64 + hi * 4];
#pragma unroll
    for (int g = 0; g < 4; ++g) {
      PackFrag pf0, pf1;
      pf0.u[0] = pack2bf(O0[4 * g + 0] * inv, O0[4 * g + 1] * inv);
      pf0.u[1] = pack2bf(O0[4 * g + 2] * inv, O0[4 * g + 3] * inv);
      *(short4v*)&cp[g * 8] = pf0.s;
      pf1.u[0] = pack2bf(O1[4 * g + 0] * inv, O1[4 * g + 1] * inv);
      pf1.u[1] = pack2bf(O1[4 * g + 2] * inv, O1[4 * g + 3] * inv);
      *(short4v*)&cp[32 + g * 8] = pf1.s;
    }
  }
#undef STAGE
#undef TILE_SYNC
}

// ---------------------------------------------------------------------------
extern "C" void kernel_launch(void* const* d_in, const int* in_sizes, int n_in,
                              void* d_out, int out_size, void* d_ws,
                              size_t ws_size, hipStream_t stream) {
  const float* hs   = (const float*)d_in[0];
  const float* mask = (const float*)d_in[1];
  const float* Wq   = (const float*)d_in[2];
  const float* bq   = (const float*)d_in[3];
  const float* Wk   = (const float*)d_in[4];
  const float* bk   = (const float*)d_in[5];
  const float* Wv   = (const float*)d_in[6];
  const float* bv   = (const float*)d_in[7];
  const float* Wo   = (const float*)d_in[8];
  const float* bo   = (const float*)d_in[9];

  char* ws = (char*)d_ws;
  short* Xb    = (short*)(ws);               // 8192x768  bf16  12.58MB
  short* Wqkvb = (short*)(ws + 12582912);    // 2304x768  bf16   3.54MB
  short* Wob   = (short*)(ws + 16121856);    // 768x768   bf16   1.18MB
  short* Qb    = (short*)(ws + 17301504);    // 8192x768  bf16  12.58MB
  short* Kb    = (short*)(ws + 29884416);    // 8192x768  bf16  12.58MB
  short* Vtg   = (short*)(ws + 42467328);    // [4][12][64][2048] 12.58MB
  short* Ctxb  = (short*)(ws + 55050240);    // 8192x768  bf16  12.58MB
  float* mbias = (float*)(ws + 67633152);    // 8192 f32  32KB

  prep<<<8480, 256, 0, stream>>>(hs, Wq, Wk, Wv, Wo, mask,
                                 Xb, Wqkvb, Wob, mbias);
  gemm_qkv<<<dim3(32, 18), 512, 0, stream>>>(Xb, Wqkvb, bq, bk, bv,
                                             Qb, Kb, Vtg);
  attn_v13<<<dim3(48, 16), 256, 0, stream>>>(Qb, Kb, Vtg, mbias, Ctxb);
  gemm_out<<<dim3(32, 6), 512, 0, stream>>>(Ctxb, Wob, bo, (float*)d_out);
}

// Round 12
// 213.318 us; speedup vs baseline: 1.1342x; 1.1342x over previous
//
#include <hip/hip_runtime.h>
#include <hip/hip_bf16.h>

#define SEQ   2048
#define NH    12
#define MTOK  8192   // 4*2048 token rows

typedef __attribute__((ext_vector_type(8))) short short8;
typedef __attribute__((ext_vector_type(4))) short short4v;
typedef __attribute__((ext_vector_type(4))) float f32x4;
typedef __attribute__((ext_vector_type(16))) float f32x16;
typedef __attribute__((ext_vector_type(2))) unsigned uint2v;

__device__ inline short f2bf(float x) {
  __hip_bfloat16 h = __float2bfloat16(x);
  return *(short*)&h;
}

#define GLL(gp, lp) __builtin_amdgcn_global_load_lds( \
    (const __attribute__((address_space(1))) void*)(gp), \
    (__attribute__((address_space(3))) void*)(lp), 16, 0, 0)

// width-4 GLL for the 64-float mask slice (lane i -> dst + i*4)
#define GLL4(gp, lp) __builtin_amdgcn_global_load_lds( \
    (const __attribute__((address_space(1))) void*)(gp), \
    (__attribute__((address_space(3))) void*)(lp), 4, 0, 0)

#define MFMA(a, b, c) __builtin_amdgcn_mfma_f32_16x16x32_bf16(a, b, c, 0, 0, 0)

// 32x32x16 bf16 MFMA — ~14% more FLOP/cycle than 16x16x32 (m119: 2495 vs
// 2176 TF) and half the instruction count per K-step.
#if !defined(__HIP_DEVICE_COMPILE__)
#define MFMA32(a, b, c) (c)
#else
#define MFMA32(a, b, c) __builtin_amdgcn_mfma_f32_32x32x16_bf16(a, b, c, 0, 0, 0)
#endif

// native exp2 (1 VALU op) hedge
#if !defined(__HIP_DEVICE_COMPILE__)
#define EXP2(x) (x)
#elif __has_builtin(__builtin_amdgcn_exp2f)
#define EXP2(x) __builtin_amdgcn_exp2f(x)
#else
#define EXP2(x) __expf((x) * 0.6931471805599453f)
#endif

// pack two fp32 -> bf16x2 dword (round-half-away; inputs finite). 3 VALU ops.
__device__ inline unsigned pack2bf(float a, float b) {
  unsigned ua = __float_as_uint(a) + 0x8000u;
  unsigned ub = __float_as_uint(b) + 0x8000u;
#if defined(__HIP_DEVICE_COMPILE__) && __has_builtin(__builtin_amdgcn_perm)
  return __builtin_amdgcn_perm(ub, ua, 0x07060302u);
#else
  return (ub & 0xFFFF0000u) | (ua >> 16);
#endif
}

// truncate-pack two fp32 -> bf16x2 (ONE VALU op: v_perm_b32). a->low, b->high.
// Truncation bias cancels in O/l since l sums the SAME truncated fragments.
__device__ inline unsigned packtrunc2(float a, float b) {
#if defined(__HIP_DEVICE_COMPILE__) && __has_builtin(__builtin_amdgcn_perm)
  return __builtin_amdgcn_perm(__float_as_uint(b), __float_as_uint(a),
                               0x07060302u);
#else
  return (__float_as_uint(b) & 0xFFFF0000u) | (__float_as_uint(a) >> 16);
#endif
}

// v_permlane32_swap_b32: ISA semantics — swaps rows 32..63 of vdst(a) with
// rows 0..31 of vsrc(b):  a'[32+i]=b[i], b'[i]=a[32+i]; others keep.
// Returns {a', b'}. Fallback: shfl(lane^32)+select, identical semantics.
__device__ inline uint2v lane32swap(unsigned a, unsigned b) {
#if defined(__HIP_DEVICE_COMPILE__) && __has_builtin(__builtin_amdgcn_permlane32_swap)
  return __builtin_amdgcn_permlane32_swap(a, b, false, false);
#else
  int lane = (int)(threadIdx.x & 63);
  unsigned xa = (unsigned)__shfl((int)a, lane ^ 32, 64);
  unsigned xb = (unsigned)__shfl((int)b, lane ^ 32, 64);
  bool hi = lane >= 32;
  uint2v r;
  r.x = hi ? xb : a;   // a': lo keeps a, hi gets lo-partner's b
  r.y = hi ? b : xa;   // b': lo gets hi-partner's a, hi keeps b
  return r;
#endif
}

union PackFrag {
  unsigned u[2];
  short4v s;
};

union Frag8 {
  unsigned u[4];
  short8 s;
};

// log2(e)*0.125 folded into Q so p = exp2(S + maskbias)
#define QSCALE 0.18033688011112042f
#define MBSCALE -14426.950408889634f  // -10000*log2(e)

// ---------------------------------------------------------------------------
// Fused prep: hs->Xb bf16 | Wq|Wk|Wv->Wqkvb, Wo->Wob | mask->mbias
// ---------------------------------------------------------------------------
__global__ __launch_bounds__(256) void prep(
    const float* __restrict__ hs, const float* __restrict__ Wq,
    const float* __restrict__ Wk, const float* __restrict__ Wv,
    const float* __restrict__ Wo, const float* __restrict__ mask,
    short* __restrict__ Xb, short* __restrict__ Wqkvb,
    short* __restrict__ Wob, float* __restrict__ mbias) {
  int bid = blockIdx.x;
  if (bid < 6144) {
    int i = bid * 256 + threadIdx.x;     // 8192*192 float4s
    float4 v = ((const float4*)hs)[i];
    short4v o;
    o[0] = f2bf(v.x); o[1] = f2bf(v.y); o[2] = f2bf(v.z); o[3] = f2bf(v.w);
    ((short4v*)Xb)[i] = o;
  } else if (bid < 6144 + 2304) {
    int idx = (bid - 6144) * 256 + threadIdx.x;  // 3072*192
    int r = idx / 192, c = (idx - r * 192) * 4;
    const float* src;
    short* dst;
    int rr;
    if (r < 768)       { src = Wq; rr = r;        dst = Wqkvb; }
    else if (r < 1536) { src = Wk; rr = r - 768;  dst = Wqkvb; }
    else if (r < 2304) { src = Wv; rr = r - 1536; dst = Wqkvb; }
    else               { src = Wo; rr = r - 2304; dst = Wob; r = rr; }
    float4 v = *(const float4*)&src[(size_t)rr * 768 + c];
    short4v o;
    o[0] = f2bf(v.x); o[1] = f2bf(v.y); o[2] = f2bf(v.z); o[3] = f2bf(v.w);
    *(short4v*)&dst[(size_t)r * 768 + c] = o;
  } else {
    int i = (bid - 6144 - 2304) * 256 + threadIdx.x;
    if (i < MTOK) mbias[i] = (1.f - mask[i]) * MBSCALE;
  }
}

// ---------------------------------------------------------------------------
// BK=64 GEMM core, 32x32x16 MFMA variant. Structure (staging, swizzle, LDS,
// 2-barrier loop, grid) is the verified R6 BK64 core UNCHANGED — only the
// fragment reads + MFMA shape + accumulator changed. Per wave: 2x2 tiles of
// 32x32 (acc 4x f32x16 = 64 VGPR, same as before), 16 MFMA32/K-step (vs 32
// half-sized). Fragment layouts HW-verified in attn_v12/v13 this session:
// A/B frag row/col = l31, k = hi*8+j; C/D col = l31, row = (r&3)+8*(r>>2)+4*hi.
// Read swizzle: LDS chunk (kk*2+hi)^(row&7), row&7 = l31&7 — uniform
// 8 lanes/bank (same class as attn's conflict-neutral reads).
// R9/R11 lesson: do NOT touch the schedule (BK32-ring and 8-phase both
// regressed); the math-shape axis is orthogonal.
// ---------------------------------------------------------------------------
#define GEMM_BK64_LOOP32(Aptr, Bptr)                                          \
  __shared__ __align__(16) short As[128 * 64];                                \
  __shared__ __align__(16) short Bs[128 * 64];                                \
  const int t = threadIdx.x;                                                  \
  const int wid = t >> 6, lane = t & 63, l31 = lane & 31, hi = lane >> 5;     \
  const int bm = blockIdx.x * 128, bn = blockIdx.y * 128;                     \
  const int mq = (wid & 1) * 64, nq = (wid >> 1) * 64;                        \
  const int srow8 = lane >> 3;                                                \
  const int schunk = lane & 7;                                                \
  const int scol = (schunk ^ srow8) * 8;                                      \
  const int rs7 = l31 & 7;                                                    \
  f32x16 acc[2][2] = {};                                                      \
  const short *gA[4], *gB[4];                                                 \
  _Pragma("unroll") for (int g = 0; g < 4; ++g) {                             \
    int row = wid * 32 + g * 8 + srow8;                                       \
    gA[g] = (Aptr) + (size_t)(bm + row) * 768 + scol;                         \
    gB[g] = (Bptr) + (size_t)(bn + row) * 768 + scol;                         \
  }                                                                           \
  for (int k0 = 0; k0 < 768; k0 += 64) {                                      \
    _Pragma("unroll") for (int g = 0; g < 4; ++g)                             \
      GLL(gA[g] + k0, &As[(wid * 32 + g * 8) * 64]);                          \
    _Pragma("unroll") for (int g = 0; g < 4; ++g)                             \
      GLL(gB[g] + k0, &Bs[(wid * 32 + g * 8) * 64]);                          \
    __syncthreads();                                                          \
    _Pragma("unroll") for (int kk = 0; kk < 4; ++kk) {                        \
      short8 a[2], b[2];                                                      \
      _Pragma("unroll") for (int mt = 0; mt < 2; ++mt)                        \
        a[mt] = *(const short8*)&As[(mq + mt * 32 + l31) * 64 +               \
                                    (((kk * 2 + hi) ^ rs7) * 8)];             \
      _Pragma("unroll") for (int nt = 0; nt < 2; ++nt)                        \
        b[nt] = *(const short8*)&Bs[(nq + nt * 32 + l31) * 64 +               \
                                    (((kk * 2 + hi) ^ rs7) * 8)];             \
      _Pragma("unroll") for (int mt = 0; mt < 2; ++mt)                        \
        _Pragma("unroll") for (int nt = 0; nt < 2; ++nt)                      \
          acc[mt][nt] = MFMA32(a[mt], b[nt], acc[mt][nt]);                    \
    }                                                                         \
    __syncthreads();                                                          \
  }

// ---------------------------------------------------------------------------
__global__ __launch_bounds__(256) void gemm_qkv(
    const short* __restrict__ A, const short* __restrict__ B,
    const float* __restrict__ bq, const float* __restrict__ bk,
    const float* __restrict__ bv, short* __restrict__ Qb,
    short* __restrict__ Kb, short* __restrict__ Vt) {
  GEMM_BK64_LOOP32(A, B)

  const int seg = bn >= 1536 ? 2 : (bn >= 768 ? 1 : 0);
  const float* bias = seg == 0 ? bq : (seg == 1 ? bk : bv);
  const int colbase = bn - seg * 768;

  if (seg < 2) {
    short* dst = seg == 0 ? Qb : Kb;
    const float sc = seg == 0 ? QSCALE : 1.f;
#pragma unroll
    for (int mt = 0; mt < 2; ++mt)
#pragma unroll
      for (int nt = 0; nt < 2; ++nt) {
        int col = colbase + nq + nt * 32 + l31;
        float bias_v = bias[col];
#pragma unroll
        for (int g = 0; g < 4; ++g)
#pragma unroll
          for (int i = 0; i < 4; ++i) {
            int row = bm + mq + mt * 32 + g * 8 + hi * 4 + i;
            dst[(size_t)row * 768 + col] =
                f2bf((acc[mt][nt][4 * g + i] + bias_v) * sc);
          }
      }
  } else {
#pragma unroll
    for (int mt = 0; mt < 2; ++mt)
#pragma unroll
      for (int nt = 0; nt < 2; ++nt) {
        int col = colbase + nq + nt * 32 + l31;
        float bias_v = bias[col];
        int h = col >> 6, d = col & 63;
#pragma unroll
        for (int g = 0; g < 4; ++g) {
          int row0 = bm + mq + mt * 32 + g * 8 + hi * 4;
          int b_ = row0 >> 11, s = row0 & 2047;
          short4v pv;
#pragma unroll
          for (int i = 0; i < 4; ++i)
            pv[i] = f2bf(acc[mt][nt][4 * g + i] + bias_v);
          *(short4v*)&Vt[(((size_t)b_ * NH + h) * 64 + d) * 2048 + s] = pv;
        }
      }
  }
}

// ---------------------------------------------------------------------------
__global__ __launch_bounds__(256) void gemm_out(
    const short* __restrict__ A, const short* __restrict__ B,
    const float* __restrict__ bias, float* __restrict__ C) {
  GEMM_BK64_LOOP32(A, B)

#pragma unroll
  for (int mt = 0; mt < 2; ++mt)
#pragma unroll
    for (int nt = 0; nt < 2; ++nt) {
      int col = bn + nq + nt * 32 + l31;
      float bias_v = bias[col];
#pragma unroll
      for (int g = 0; g < 4; ++g)
#pragma unroll
        for (int i = 0; i < 4; ++i) {
          int row = bm + mq + mt * 32 + g * 8 + hi * 4 + i;
          C[(size_t)row * 768 + col] = acc[mt][nt][4 * g + i] + bias_v;
        }
    }
}

// ---------------------------------------------------------------------------
// attn_v13 (R6, verified 68.8us): v12 32x32-MFMA math + ring-3 LDS, counted
// vmcnt(5), mask in LDS. Unchanged (R8's setprio graft regressed; reverted).
// ---------------------------------------------------------------------------
__global__ __launch_bounds__(256, 3) void attn_v13(
    const short* __restrict__ Qb, const short* __restrict__ Kb,
    const short* __restrict__ Vt, const float* __restrict__ maskb,
    short* __restrict__ Ctx) {
  __shared__ __align__(16) short Ks[3][64 * 64];   // [slot][key][dchunk^swz]
  __shared__ __align__(16) short Vs[3][64 * 64];   // [slot][d][keychunk^swz]
  __shared__ __align__(16) float Mbs[3][64];       // [slot][key] mask bias
  const int t = threadIdx.x;
  const int w = t >> 6, lane = t & 63, l31 = lane & 31, hi = lane >> 5;
  const int bh = blockIdx.x, b = bh / NH, h = bh % NH;
  const int q0 = blockIdx.y * 128;

  // Q B-fragments: qb[kc] = Q[q=l31][d = kc*16 + hi*8 + 0..7]
  short8 qb[4];
  {
    int rowq = b * 2048 + q0 + w * 32 + l31;
    const short* qp = &Qb[(size_t)rowq * 768 + h * 64 + hi * 8];
#pragma unroll
    for (int kc = 0; kc < 4; ++kc) qb[kc] = *(const short8*)&qp[kc * 16];
  }

  f32x16 O0 = {}, O1 = {}, lacc = {};
  short8 ones8;
#pragma unroll
  for (int j = 0; j < 8; ++j) ones8[j] = (short)0x3F80;  // bf16 1.0

  // staging: each wave stages 16 K-rows + 16 V-rows + the 64-float mb slice
  const int r0 = w * 16 + (lane >> 3);
  const int pc = lane & 7;
  const int swz0 = (pc ^ (r0 & 7)) * 8;
  const int swz1 = (pc ^ ((r0 + 8) & 7)) * 8;
  const short* gK0 = Kb + (size_t)(b * 2048 + r0) * 768 + h * 64 + swz0;
  const short* gK1 = Kb + (size_t)(b * 2048 + r0 + 8) * 768 + h * 64 + swz1;
  const short* gV0 = Vt + ((size_t)bh * 64 + r0) * 2048 + swz0;
  const short* gV1 = Vt + ((size_t)bh * 64 + r0 + 8) * 2048 + swz1;
  const float* gmb = maskb + b * 2048 + lane;  // per-lane f32 for GLL4
  const int rs = l31 & 7;  // read-side swizzle key (row&7 for both 32-blocks)

  // issue the 5 GLLs for tile tt into ring slot s (mb first -> group of 5)
#define STAGE(tt, s) do {                                                     \
    const size_t kn = (size_t)(((tt) & 31) * 64);                             \
    GLL4(gmb + kn, &Mbs[s][0]);                                               \
    GLL(gK0 + kn * 768, &Ks[s][(w * 16) * 64]);                               \
    GLL(gK1 + kn * 768, &Ks[s][(w * 16 + 8) * 64]);                           \
    GLL(gV0 + kn, &Vs[s][(w * 16) * 64]);                                     \
    GLL(gV1 + kn, &Vs[s][(w * 16 + 8) * 64]);                                 \
  } while (0)

#define TILE_SYNC() do {                                                      \
    asm volatile("s_waitcnt vmcnt(5)" ::: "memory");                          \
    __builtin_amdgcn_s_barrier();                                             \
    __builtin_amdgcn_sched_barrier(0);                                        \
  } while (0)

  // prologue: tiles 0,1 in flight; wait for tile 0 only (vmcnt(5) leaves
  // tile 1's five GLLs outstanding; also drains the older Q loads).
  STAGE(0, 0);
  STAGE(1, 1);
  TILE_SYNC();

  int cur = 0;
  for (int ti = 0; ti < 32; ++ti) {
    const int nx2 = (cur == 0) ? 2 : cur - 1;  // (ti+2)%3
    STAGE(ti + 2, nx2);                        // depth-2 prefetch (wraps; unread)

    short8 pfrag[4];  // PV B-fragments, one per 16-key chunk

#pragma unroll
    for (int kb2 = 0; kb2 < 2; ++kb2) {
      // S^T[key][q], keys kb2*32..+31: seed with maskbias from LDS
      // (acc reg 4g+i holds key kb2*32 + 8g + 4hi + i)
      f32x16 S;
#pragma unroll
      for (int g = 0; g < 4; ++g) {
        f32x4 m4 = *(const f32x4*)&Mbs[cur][kb2 * 32 + g * 8 + hi * 4];
        S[4 * g + 0] = m4[0]; S[4 * g + 1] = m4[1];
        S[4 * g + 2] = m4[2]; S[4 * g + 3] = m4[3];
      }
      // K A-frags: K[key = kb2*32 + l31][d = kc*16 + hi*8 + 0..7]
#pragma unroll
      for (int kc = 0; kc < 4; ++kc) {
        short8 ka = *(const short8*)&Ks[cur][(kb2 * 32 + l31) * 64 +
                                            (((kc * 2 + hi) ^ rs) * 8)];
        S = MFMA32(ka, qb[kc], S);
      }
      // p = exp2(S) -> truncate-pack -> dwords pk[g][m] = keys 8g+4hi+{2m,2m+1}
      unsigned pk[4][2];
#pragma unroll
      for (int g = 0; g < 4; ++g) {
        float p0 = EXP2(S[4 * g + 0]);
        float p1 = EXP2(S[4 * g + 1]);
        float p2 = EXP2(S[4 * g + 2]);
        float p3 = EXP2(S[4 * g + 3]);
        pk[g][0] = packtrunc2(p0, p1);
        pk[g][1] = packtrunc2(p2, p3);
      }
      // permlane32_swap -> B-frags (keys hi*8+{0..7} per 16-key chunk)
#pragma unroll
      for (int half = 0; half < 2; ++half) {
        Frag8 f;
        uint2v ra = lane32swap(pk[half * 2][0], pk[half * 2 + 1][0]);
        uint2v rb = lane32swap(pk[half * 2][1], pk[half * 2 + 1][1]);
        f.u[0] = ra.x;  // keys +{0,1}
        f.u[1] = rb.x;  // keys +{2,3}
        f.u[2] = ra.y;  // keys +{4,5}
        f.u[3] = rb.y;  // keys +{6,7}
        pfrag[kb2 * 2 + half] = f.s;
      }
    }

    // l += 1 . P^T  (every D row = running l[q]; consumes truncated pfrag)
#pragma unroll
    for (int c = 0; c < 4; ++c) lacc = MFMA32(ones8, pfrag[c], lacc);

    // O^T += V^T . P^T : A = V^T[d = db*32 + l31][key = c*16 + hi*8 + 0..7]
#pragma unroll
    for (int c = 0; c < 4; ++c) {
      short8 av0 = *(const short8*)&Vs[cur][(l31) * 64 +
                                           (((c * 2 + hi) ^ rs) * 8)];
      short8 av1 = *(const short8*)&Vs[cur][(32 + l31) * 64 +
                                           (((c * 2 + hi) ^ rs) * 8)];
      O0 = MFMA32(av0, pfrag[c], O0);
      O1 = MFMA32(av1, pfrag[c], O1);
    }

    TILE_SYNC();  // tile ti+1 ready; tile ti+2's 5 GLLs stay in flight
    cur = (cur == 2) ? 0 : cur + 1;
  }

  // epilogue: O reg 4g+i = O^T[d = db*32 + 8g + 4hi + i][q = l31]
  {
    float inv = 1.f / lacc[0];
    int rowq = b * 2048 + q0 + w * 32 + l31;
    short* cp = &Ctx[(size_t)rowq * 768 + h * 64 + hi * 4];
#pragma unroll
    for (int g = 0; g < 4; ++g) {
      PackFrag pf0, pf1;
      pf0.u[0] = pack2bf(O0[4 * g + 0] * inv, O0[4 * g + 1] * inv);
      pf0.u[1] = pack2bf(O0[4 * g + 2] * inv, O0[4 * g + 3] * inv);
      *(short4v*)&cp[g * 8] = pf0.s;
      pf1.u[0] = pack2bf(O1[4 * g + 0] * inv, O1[4 * g + 1] * inv);
      pf1.u[1] = pack2bf(O1[4 * g + 2] * inv, O1[4 * g + 3] * inv);
      *(short4v*)&cp[32 + g * 8] = pf1.s;
    }
  }
#undef STAGE
#undef TILE_SYNC
}

// ---------------------------------------------------------------------------
extern "C" void kernel_launch(void* const* d_in, const int* in_sizes, int n_in,
                              void* d_out, int out_size, void* d_ws,
                              size_t ws_size, hipStream_t stream) {
  const float* hs   = (const float*)d_in[0];
  const float* mask = (const float*)d_in[1];
  const float* Wq   = (const float*)d_in[2];
  const float* bq   = (const float*)d_in[3];
  const float* Wk   = (const float*)d_in[4];
  const float* bk   = (const float*)d_in[5];
  const float* Wv   = (const float*)d_in[6];
  const float* bv   = (const float*)d_in[7];
  const float* Wo   = (const float*)d_in[8];
  const float* bo   = (const float*)d_in[9];

  char* ws = (char*)d_ws;
  short* Xb    = (short*)(ws);               // 8192x768  bf16  12.58MB
  short* Wqkvb = (short*)(ws + 12582912);    // 2304x768  bf16   3.54MB
  short* Wob   = (short*)(ws + 16121856);    // 768x768   bf16   1.18MB
  short* Qb    = (short*)(ws + 17301504);    // 8192x768  bf16  12.58MB
  short* Kb    = (short*)(ws + 29884416);    // 8192x768  bf16  12.58MB
  short* Vtg   = (short*)(ws + 42467328);    // [4][12][64][2048] 12.58MB
  short* Ctxb  = (short*)(ws + 55050240);    // 8192x768  bf16  12.58MB
  float* mbias = (float*)(ws + 67633152);    // 8192 f32  32KB

  prep<<<8480, 256, 0, stream>>>(hs, Wq, Wk, Wv, Wo, mask,
                                 Xb, Wqkvb, Wob, mbias);
  gemm_qkv<<<dim3(64, 18), 256, 0, stream>>>(Xb, Wqkvb, bq, bk, bv,
                                             Qb, Kb, Vtg);
  attn_v13<<<dim3(48, 16), 256, 0, stream>>>(Qb, Kb, Vtg, mbias, Ctxb);
  gemm_out<<<dim3(64, 6), 256, 0, stream>>>(Ctxb, Wob, bo, (float*)d_out);
}